// Round 2
// baseline (183.443 us; speedup 1.0000x reference)
//
#include <hip/hip_runtime.h>
#include <math.h>

#define DIMX 16
#define SECX 16
#define SUBX 16
#define EX   256
#define BX   128
#define SLX  64

// output offsets (floats)
#define O_TZ1      0
#define O_TZ2      1024
#define O_FWD      2048
#define O_EQUI     18432
#define O_ATTN     18433
#define O_ORTH     35841
#define O_PAR      35842
#define O_COMM     35843
#define O_SPARSE   35844
#define O_SECLOSS  35845
#define O_SUB      35846

// ---------------- kernel A1: linear head, softmaxes, switch, fprob, w, sector_loss, attn_score ----------------
__global__ void k_prob(const float* __restrict__ mean, const float* __restrict__ logvar,
                       const float* __restrict__ latent, const float* __restrict__ lin_w,
                       const float* __restrict__ lin_b, const float* __restrict__ gumbel,
                       float* __restrict__ out, float* __restrict__ w_ws, double* __restrict__ acc)
{
    int b = blockIdx.x;
    int t = threadIdx.x;
    __shared__ float feat[64];
    __shared__ float prob[288];
    __shared__ float red[16];
    if (t < 64) {
        int k = t;
        float v;
        if (k < 16)       v = mean[b*16 + k];
        else if (k < 32)  v = expf(0.5f * logvar[b*16 + (k-16)]);
        else if (k < 48)  v = mean[(64+b)*16 + (k-32)];
        else              v = expf(0.5f * mean[(64+b)*16 + (k-48)]);   // std2 = exp(0.5*mean[sl:]) per reference
        feat[k] = v;
    }
    __syncthreads();
    for (int j = t; j < 288; j += 256) {
        float a = lin_b[j];
        const float* wr = lin_w + j*64;
        #pragma unroll
        for (int k = 0; k < 64; ++k) a += feat[k]*wr[k];
        prob[j] = a;
    }
    __syncthreads();
    if (t < 16) {
        int s = t;
        float l0 = prob[2*s], l1 = prob[2*s+1];
        // p = softmax(logits)
        float M = fmaxf(l0,l1);
        float e0 = expf(l0-M), e1 = expf(l1-M);
        float Z = e0+e1;
        float p0 = e0/Z, p1 = e1/Z;
        // ls = log_softmax(p)
        float M2 = fmaxf(p0,p1);
        float lse = M2 + logf(expf(p0-M2)+expf(p1-M2));
        float ls0 = p0 - lse, ls1 = p1 - lse;
        float z1v = latent[b*16+s], z2v = latent[(64+b)*16+s];
        int tt = (fabsf(z1v - z2v) > 0.2f) ? 1 : 0;
        red[s] = -(tt ? ls1 : ls0);
        // gumbel attn, tau = 1e-4
        int r = b*16 + s;
        float x0 = (l0 + gumbel[2*r])   * 10000.0f;
        float x1 = (l1 + gumbel[2*r+1]) * 10000.0f;
        float Ma = fmaxf(x0,x1);
        float a0 = expf(x0-Ma), a1 = expf(x1-Ma);
        float Za = a0+a1;
        a0 /= Za; a1 /= Za;
        float sw = ((a0 >= 0.5f) || (a1 > 0.5f)) ? a1 : 0.0f;
        out[O_ATTN + b*272 + s] = sw;
        // fprob softmax over 16
        const float* fl = &prob[32 + s*16];
        float mf = fl[0];
        #pragma unroll
        for (int u = 1; u < 16; ++u) mf = fmaxf(mf, fl[u]);
        float ex[16]; float Zf = 0.f;
        #pragma unroll
        for (int u = 0; u < 16; ++u) { ex[u] = expf(fl[u]-mf); Zf += ex[u]; }
        float rZ = 1.0f/Zf;
        #pragma unroll
        for (int u = 0; u < 16; ++u) {
            float fp = ex[u]*rZ;
            out[O_ATTN + b*272 + 16 + s*16 + u] = fp;
            w_ws[b*256 + s*16 + u] = sw*fp;
        }
    }
    __syncthreads();
    if (t == 0) {
        float s = 0.f;
        for (int i = 0; i < 16; ++i) s += red[i];
        atomicAdd(&acc[0], (double)s);
    }
}

// ---------------- kernel A2: sub_syms (out) and S ----------------
__global__ void k_ssyms(const float* __restrict__ ge, const float* __restrict__ w_ws,
                        float* __restrict__ S_ws, float* __restrict__ out)
{
    int b = blockIdx.x;
    int t = threadIdx.x;   // element (i,j) flattened
    __shared__ float wrow[256];
    wrow[t] = w_ws[b*256 + t];
    __syncthreads();
    float Stot = 0.f;
    for (int s = 0; s < 16; ++s) {
        float a = 0.f;
        #pragma unroll
        for (int u = 0; u < 16; ++u)
            a += wrow[s*16+u] * ge[(s*16+u)*256 + t];
        out[O_SUB + b*4096 + s*256 + t] = a;
        Stot += a;
    }
    S_ws[b*256 + t] = Stot;
}

// ---------------- kernel B: 384 matrix exponentials (scaling-squaring + Taylor-12) ----------------
__global__ void k_expm(const float* __restrict__ ge, const float* __restrict__ S_ws,
                       float* __restrict__ syms, float* __restrict__ fwdS,
                       float* __restrict__ invS, float* __restrict__ out)
{
    int bid = blockIdx.x;
    int t = threadIdx.x;
    const float* src; float sign = 1.f; float* dst; float* dst2 = nullptr;
    if (bid < 256)      { src = ge + bid*256;         dst = syms + bid*256; }
    else if (bid < 320) { int b = bid-256; src = S_ws + b*256; dst = fwdS + b*256; dst2 = out + O_FWD + b*256; }
    else                { int b = bid-320; src = S_ws + b*256; sign = -1.f; dst = invS + b*256; }

    __shared__ float As[256], T[256], P[256];
    __shared__ float rowsum[16];
    __shared__ int sh_s;
    float a = src[t];
    As[t] = a;
    __syncthreads();
    if (t < 16) {
        float rs = 0.f;
        #pragma unroll
        for (int k = 0; k < 16; ++k) rs += fabsf(As[t*16+k]);
        rowsum[t] = rs;
    }
    __syncthreads();
    if (t == 0) {
        float nrm = 0.f;
        for (int i = 0; i < 16; ++i) nrm = fmaxf(nrm, rowsum[i]);
        int s = 0;
        if (nrm > 0.25f) {
            s = (int)ceilf(log2f(nrm * 4.0f));
            if (s < 0) s = 0;
        }
        sh_s = s;
    }
    __syncthreads();
    int sq = sh_s;
    float scale = sign * exp2f((float)(-sq));
    int i = t >> 4, j = t & 15;
    float as = a * scale;
    As[t] = as;
    T[t]  = ((i==j) ? 1.0f : 0.0f) + as;
    P[t]  = as;
    __syncthreads();
    for (int k = 2; k <= 12; ++k) {
        float accv = 0.f;
        #pragma unroll
        for (int m = 0; m < 16; ++m) accv += P[i*16+m]*As[m*16+j];
        float rk = 1.0f/(float)k;
        __syncthreads();
        float term = accv * rk;
        P[t] = term;
        T[t] += term;
        __syncthreads();
    }
    for (int q = 0; q < sq; ++q) {
        float accv = 0.f;
        #pragma unroll
        for (int m = 0; m < 16; ++m) accv += T[i*16+m]*T[m*16+j];
        __syncthreads();
        T[t] = accv;
        __syncthreads();
    }
    dst[t] = T[t];
    if (dst2) dst2[t] = T[t];
}

// ---------------- kernel C: diff = z - z@syms[e], row norms (inv), sparse ----------------
__global__ void k_diff(const float* __restrict__ latent, const float* __restrict__ syms,
                       float* __restrict__ diff, float* __restrict__ rinv, double* __restrict__ acc)
{
    int e = blockIdx.x;
    int t = threadIdx.x;
    __shared__ float zsh[2048];
    __shared__ float ssh[256];
    __shared__ float dsh[2048];
    __shared__ float red[256];
    ssh[t] = syms[e*256+t];
    #pragma unroll
    for (int q = 0; q < 8; ++q) zsh[t+256*q] = latent[t+256*q];
    __syncthreads();
    #pragma unroll
    for (int q = 0; q < 8; ++q) {
        int idx = t + 256*q;
        int b = idx >> 4, d = idx & 15;
        float a = 0.f;
        #pragma unroll
        for (int k = 0; k < 16; ++k) a += zsh[b*16+k]*ssh[k*16+d];
        float v = zsh[idx] - a;
        dsh[idx] = v;
        diff[e*2048 + idx] = v;
    }
    __syncthreads();
    float part = 0.f;
    if (t < 128) {
        float sum = 0.f, mx = 0.f;
        #pragma unroll
        for (int d = 0; d < 16; ++d) {
            float v = dsh[t*16+d];
            float v2 = v*v;
            sum += v2; mx = fmaxf(mx, v2);
        }
        float sm = sum - mx;
        part = sm*sm;
        rinv[e*128+t] = 1.0f/sqrtf(sum);
    }
    red[t] = part;
    __syncthreads();
    for (int off = 128; off > 0; off >>= 1) { if (t < off) red[t] += red[t+off]; __syncthreads(); }
    if (t == 0) atomicAdd(&acc[1], (double)red[0]);
}

// ---------------- kernel D: parallel = mean(-log((dd/nn)^2 + 1e-9)) ----------------
__global__ void __launch_bounds__(256) k_parallel(const float* __restrict__ diff,
                                                  const float* __restrict__ rinv,
                                                  double* __restrict__ acc)
{
    int bid = blockIdx.x;
    int s    = bid >> 8;
    int tile = bid & 255;
    int tm = tile >> 4, tn = tile & 15;
    int baseM = s*2048 + tm*128;   // row index into diff (32768 x 16)
    int baseN = s*2048 + tn*128;
    __shared__ __attribute__((aligned(16))) float tM[2048];
    __shared__ __attribute__((aligned(16))) float tN[2048];
    __shared__ float rM[128], rN[128];
    __shared__ float red[256];
    int t = threadIdx.x;
    #pragma unroll
    for (int q = 0; q < 8; ++q) {
        tM[t+256*q] = diff[baseM*16 + t + 256*q];
        tN[t+256*q] = diff[baseN*16 + t + 256*q];
    }
    if (t < 128) rM[t] = rinv[baseM + t];
    else         rN[t-128] = rinv[baseN + (t-128)];
    __syncthreads();
    int rp = t >> 2;      // 0..63  -> rows 2*rp, 2*rp+1
    int cg = t & 3;       // column group (interleaved)
    int m0 = rp*2;
    float vm0[16], vm1[16];
    #pragma unroll
    for (int k = 0; k < 16; ++k) { vm0[k] = tM[m0*16+k]; vm1[k] = tM[(m0+1)*16+k]; }
    float r0 = rM[m0], r1 = rM[m0+1];
    float accf = 0.f;
    for (int jj = 0; jj < 32; ++jj) {
        int nj = cg + 4*jj;
        float nv[16];
        const float4* pn = (const float4*)(&tN[nj*16]);
        float4* nvp = (float4*)nv;
        nvp[0] = pn[0]; nvp[1] = pn[1]; nvp[2] = pn[2]; nvp[3] = pn[3];
        float d0 = 0.f, d1 = 0.f;
        #pragma unroll
        for (int k = 0; k < 16; ++k) { d0 += vm0[k]*nv[k]; d1 += vm1[k]*nv[k]; }
        float rn = rN[nj];
        float ra = d0*r0*rn;
        float rb = d1*r1*rn;
        accf -= logf(ra*ra + 1e-9f);
        accf -= logf(rb*rb + 1e-9f);
    }
    red[t] = accf;
    __syncthreads();
    for (int off = 128; off > 0; off >>= 1) { if (t < off) red[t] += red[t+off]; __syncthreads(); }
    if (t == 0) atomicAdd(&acc[2], (double)red[0]);
}

// ---------------- kernel E: orth (off-diagonal sector tiles only) ----------------
__global__ void k_orth(const float* __restrict__ diff, const float* __restrict__ rinv,
                       const int* __restrict__ sec_idx, double* __restrict__ acc)
{
    int bid = blockIdx.x;        // 0..239
    int sm = bid / 15;
    int rr = bid % 15;
    int sn = rr + (rr >= sm ? 1 : 0);
    int em = sm*16 + sec_idx[sm];
    int en = sn*16 + sec_idx[sn];
    int baseM = em*128, baseN = en*128;
    __shared__ __attribute__((aligned(16))) float tM[2048];
    __shared__ __attribute__((aligned(16))) float tN[2048];
    __shared__ float rM[128], rN[128];
    __shared__ float red[256];
    int t = threadIdx.x;
    #pragma unroll
    for (int q = 0; q < 8; ++q) {
        tM[t+256*q] = diff[baseM*16 + t + 256*q];
        tN[t+256*q] = diff[baseN*16 + t + 256*q];
    }
    if (t < 128) rM[t] = rinv[baseM + t];
    else         rN[t-128] = rinv[baseN + (t-128)];
    __syncthreads();
    int rp = t >> 2;
    int cg = t & 3;
    int m0 = rp*2;
    float vm0[16], vm1[16];
    #pragma unroll
    for (int k = 0; k < 16; ++k) { vm0[k] = tM[m0*16+k]; vm1[k] = tM[(m0+1)*16+k]; }
    float r0 = rM[m0], r1 = rM[m0+1];
    float accf = 0.f;
    for (int jj = 0; jj < 32; ++jj) {
        int nj = cg + 4*jj;
        float nv[16];
        const float4* pn = (const float4*)(&tN[nj*16]);
        float4* nvp = (float4*)nv;
        nvp[0] = pn[0]; nvp[1] = pn[1]; nvp[2] = pn[2]; nvp[3] = pn[3];
        float d0 = 0.f, d1 = 0.f;
        #pragma unroll
        for (int k = 0; k < 16; ++k) { d0 += vm0[k]*nv[k]; d1 += vm1[k]*nv[k]; }
        float rn = rN[nj];
        float ra = d0*r0*rn;
        float rb = d1*r1*rn;
        accf += ra*ra + rb*rb;
    }
    red[t] = accf;
    __syncthreads();
    for (int off = 128; off > 0; off >>= 1) { if (t < off) red[t] += red[t+off]; __syncthreads(); }
    if (t == 0) atomicAdd(&acc[3], (double)red[0]);
}

// ---------------- kernel F: commut pair values ----------------
__global__ void k_commut(const float* __restrict__ ge, float* __restrict__ c_pairs)
{
    __shared__ float G[4096];    // ge[16k], k=0..15
    __shared__ float gA[256], gB[256];
    __shared__ float red[256];
    int t = threadIdx.x;
    int idx = blockIdx.x;
    int a2 = 0, cnt = 15, rem = idx;
    while (rem >= cnt) { rem -= cnt; a2++; cnt--; }
    int b2 = a2 + 1 + rem;
    #pragma unroll
    for (int q = 0; q < 16; ++q) {
        int ii = t + 256*q;
        int k = ii >> 8, x = ii & 255;
        G[ii] = ge[k*16*256 + x];
    }
    gA[t] = ge[a2*256+t];
    gB[t] = ge[b2*256+t];
    __syncthreads();
    int i = t >> 4, j = t & 15;
    float v1 = 0.f, v2 = 0.f;
    #pragma unroll
    for (int k = 0; k < 16; ++k) {
        v1 += gA[i*16+k]*G[k*256 + b2*16 + j];   // R[a,i,b,j]
        v2 += gB[i*16+k]*G[k*256 + a2*16 + j];   // R[b,i,a,j]
    }
    float d = v1 - v2;
    red[t] = d*d;
    __syncthreads();
    for (int off = 128; off > 0; off >>= 1) { if (t < off) red[t] += red[t+off]; __syncthreads(); }
    if (t == 0) c_pairs[idx] = 2.0f*red[0];
}

// ---------------- kernel G: tz1, tz2, equivariant (1024 threads: b in [0,64), d in [0,16)) ----------------
__global__ void k_tz(const float* __restrict__ latent, const float* __restrict__ fwdS,
                     const float* __restrict__ invS, float* __restrict__ out, double* __restrict__ acc)
{
    int g = blockIdx.x*256 + threadIdx.x;  // 0..1023
    int b = g >> 4, d = g & 15;            // b < 64
    float t1 = 0.f, t2 = 0.f;
    #pragma unroll
    for (int k = 0; k < 16; ++k) {
        t1 += latent[b*16+k]      * fwdS[b*256 + k*16 + d];
        t2 += latent[(64+b)*16+k] * invS[b*256 + k*16 + d];
    }
    out[O_TZ1 + g] = t1;
    out[O_TZ2 + g] = t2;
    float z1v = latent[b*16+d], z2v = latent[(64+b)*16+d];
    float ep = (t2 - z1v)*(t2 - z1v) + (t1 - z2v)*(t1 - z2v);
    __shared__ float red[256];
    int t = threadIdx.x;
    red[t] = ep;
    __syncthreads();
    for (int off = 128; off > 0; off >>= 1) { if (t < off) red[t] += red[t+off]; __syncthreads(); }
    if (t == 0) atomicAdd(&acc[4], (double)red[0]);
}

// ---------------- kernel H: final scalar assembly ----------------
__global__ void k_final(const float* __restrict__ c_pairs, const double* __restrict__ acc,
                        float* __restrict__ out)
{
    int t = threadIdx.x;
    __shared__ float red[128];
    float v = 0.f;
    if (t < 120) v = (float)(120 - t) * c_pairs[t];
    red[t] = v;
    __syncthreads();
    for (int off = 64; off > 0; off >>= 1) { if (t < off) red[t] += red[t+off]; __syncthreads(); }
    if (t == 0) {
        out[O_COMM]    = red[0] / 16777216.0f;                 // /(DIM*E)^2
        out[O_EQUI]    = (float)(acc[4] / 1024.0);
        out[O_ORTH]    = (float)(acc[3] / (2048.0*2048.0));
        out[O_PAR]     = (float)(acc[2] / 67108864.0);         // 16*2048*2048
        out[O_SPARSE]  = (float)(acc[1] / 32768.0);
        out[O_SECLOSS] = (float)(acc[0] / 64.0);
    }
}

extern "C" void kernel_launch(void* const* d_in, const int* in_sizes, int n_in,
                              void* d_out, int out_size, void* d_ws, size_t ws_size,
                              hipStream_t stream)
{
    const float* mean    = (const float*)d_in[0];
    const float* logvar  = (const float*)d_in[1];
    const float* latent  = (const float*)d_in[2];
    const float* ge      = (const float*)d_in[3];
    const float* lin_w   = (const float*)d_in[4];
    const float* lin_b   = (const float*)d_in[5];
    const float* gumbel  = (const float*)d_in[6];
    const int*   sec_idx = (const int*)d_in[7];
    float* out = (float*)d_out;

    char* ws = (char*)d_ws;
    double* acc     = (double*)ws;          // 5 doubles used
    float* c_pairs  = (float*)(ws + 64);    // 120 floats
    float* fbase    = (float*)(ws + 1024);
    float* w_ws = fbase;                    // 16384
    float* S_ws = fbase + 16384;            // 16384
    float* syms = fbase + 32768;            // 65536
    float* fwdS = fbase + 98304;            // 16384
    float* invS = fbase + 114688;           // 16384
    float* diff = fbase + 131072;           // 524288
    float* rinv = fbase + 655360;           // 32768   (total ~2.75 MB)

    hipMemsetAsync(ws, 0, 1024, stream);
    k_prob   <<<64,   256, 0, stream>>>(mean, logvar, latent, lin_w, lin_b, gumbel, out, w_ws, acc);
    k_ssyms  <<<64,   256, 0, stream>>>(ge, w_ws, S_ws, out);
    k_expm   <<<384,  256, 0, stream>>>(ge, S_ws, syms, fwdS, invS, out);
    k_diff   <<<256,  256, 0, stream>>>(latent, syms, diff, rinv, acc);
    k_parallel<<<4096,256, 0, stream>>>(diff, rinv, acc);
    k_orth   <<<240,  256, 0, stream>>>(diff, rinv, sec_idx, acc);
    k_commut <<<120,  256, 0, stream>>>(ge, c_pairs);
    k_tz     <<<4,    256, 0, stream>>>(latent, fwdS, invS, out, acc);
    k_final  <<<1,    128, 0, stream>>>(c_pairs, acc, out);
}

// Round 3
// 143.079 us; speedup vs baseline: 1.2821x; 1.2821x over previous
//
#include <hip/hip_runtime.h>
#include <math.h>

// output offsets (floats)
#define O_TZ1      0
#define O_TZ2      1024
#define O_FWD      2048
#define O_EQUI     18432
#define O_ATTN     18433
#define O_ORTH     35841
#define O_PAR      35842
#define O_COMM     35843
#define O_SPARSE   35844
#define O_SECLOSS  35845
#define O_SUB      35846

// ---------------- shared device helpers ----------------

__device__ __forceinline__ void block_reduce_to(float v, float* red, int t, double* dst, float scale)
{
    red[t] = v;
    __syncthreads();
    for (int off = 128; off > 0; off >>= 1) { if (t < off) red[t] += red[t+off]; __syncthreads(); }
    if (t == 0) atomicAdd(dst, (double)(red[0] * scale));
}

// expm via scaling-squaring + Taylor-12; sm must have >= 785 floats, shi a shared int
__device__ __forceinline__ void expm_block(const float* __restrict__ src, float sign,
                                           float* __restrict__ dst, float* __restrict__ dst2,
                                           float* sm, int* shi, int t)
{
    float* As = sm; float* T = sm + 256; float* P = sm + 512; float* rowsum = sm + 768;
    float a = src[t];
    As[t] = a;
    __syncthreads();
    if (t < 16) {
        float rs = 0.f;
        #pragma unroll
        for (int k = 0; k < 16; ++k) rs += fabsf(As[t*16+k]);
        rowsum[t] = rs;
    }
    __syncthreads();
    if (t == 0) {
        float nrm = 0.f;
        for (int i = 0; i < 16; ++i) nrm = fmaxf(nrm, rowsum[i]);
        int s = 0;
        if (nrm > 0.25f) { s = (int)ceilf(log2f(nrm * 4.0f)); if (s < 0) s = 0; }
        *shi = s;
    }
    __syncthreads();
    int sq = *shi;
    float scale = sign * exp2f((float)(-sq));
    int i = t >> 4, j = t & 15;
    float as = a * scale;
    As[t] = as;
    T[t]  = ((i==j) ? 1.0f : 0.0f) + as;
    P[t]  = as;
    __syncthreads();
    for (int k = 2; k <= 12; ++k) {
        float accv = 0.f;
        #pragma unroll
        for (int m = 0; m < 16; ++m) accv += P[i*16+m]*As[m*16+j];
        float rk = 1.0f/(float)k;
        __syncthreads();
        float term = accv * rk;
        P[t] = term;
        T[t] += term;
        __syncthreads();
    }
    for (int q = 0; q < sq; ++q) {
        float accv = 0.f;
        #pragma unroll
        for (int m = 0; m < 16; ++m) accv += T[i*16+m]*T[m*16+j];
        __syncthreads();
        T[t] = accv;
        __syncthreads();
    }
    dst[t] = T[t];
    if (dst2) dst2[t] = T[t];
}

// gram-tile core: 128x128 tile, 4 rows/thread, all loads from global (L2-resident diff)
template <bool DO_LOG>
__device__ __forceinline__ float tile_core(const float* __restrict__ diff,
                                           const float* __restrict__ rinv,
                                           int baseM, int baseN, int t)
{
    int rp = t >> 3, cg = t & 7;
    int r0 = baseM + rp*4;
    float vm[4][16];
    float ri[4];
    #pragma unroll
    for (int i = 0; i < 4; ++i) {
        const float4* p = (const float4*)(diff + (size_t)(r0+i)*16);
        float4 x0 = p[0], x1 = p[1], x2 = p[2], x3 = p[3];
        vm[i][0]=x0.x; vm[i][1]=x0.y; vm[i][2]=x0.z; vm[i][3]=x0.w;
        vm[i][4]=x1.x; vm[i][5]=x1.y; vm[i][6]=x1.z; vm[i][7]=x1.w;
        vm[i][8]=x2.x; vm[i][9]=x2.y; vm[i][10]=x2.z; vm[i][11]=x2.w;
        vm[i][12]=x3.x; vm[i][13]=x3.y; vm[i][14]=x3.z; vm[i][15]=x3.w;
        ri[i] = rinv[r0+i];
    }
    float accf = 0.f;
    #pragma unroll 2
    for (int jj = 0; jj < 16; ++jj) {
        int nj = baseN + cg + 8*jj;
        const float4* p = (const float4*)(diff + (size_t)nj*16);
        float4 x0 = p[0], x1 = p[1], x2 = p[2], x3 = p[3];
        float nv[16];
        nv[0]=x0.x; nv[1]=x0.y; nv[2]=x0.z; nv[3]=x0.w;
        nv[4]=x1.x; nv[5]=x1.y; nv[6]=x1.z; nv[7]=x1.w;
        nv[8]=x2.x; nv[9]=x2.y; nv[10]=x2.z; nv[11]=x2.w;
        nv[12]=x3.x; nv[13]=x3.y; nv[14]=x3.z; nv[15]=x3.w;
        float rn = rinv[nj];
        #pragma unroll
        for (int i = 0; i < 4; ++i) {
            float d = 0.f;
            #pragma unroll
            for (int k = 0; k < 16; ++k) d += vm[i][k]*nv[k];
            float ra = d * ri[i] * rn;
            float x = ra*ra + 1e-9f;
            if (DO_LOG) accf += __log2f(x);
            else        accf += ra*ra;
        }
    }
    return accf;
}

// ---------------- K1: [0,64) prob+ssyms | [64,320) expm(ge) | [320,440) commut ----------------
__global__ void k_stage1(const float* __restrict__ mean, const float* __restrict__ logvar,
                         const float* __restrict__ latent, const float* __restrict__ ge,
                         const float* __restrict__ lin_w, const float* __restrict__ lin_b,
                         const float* __restrict__ gumbel,
                         float* __restrict__ out, float* __restrict__ S_ws,
                         float* __restrict__ syms, float* __restrict__ c_pairs,
                         double* __restrict__ acc)
{
    __shared__ float smem[4864];
    __shared__ int shi;
    int bid = blockIdx.x;
    int t = threadIdx.x;

    if (bid < 64) {
        // ---- prob + ssyms for b = bid ----
        int b = bid;
        float* feat = smem;            // 64
        float* probb = smem + 64;      // 288
        float* red16 = smem + 352;     // 16
        float* wrow = smem + 368;      // 256
        if (t < 64) {
            int k = t; float v;
            if (k < 16)       v = mean[b*16 + k];
            else if (k < 32)  v = expf(0.5f * logvar[b*16 + (k-16)]);
            else if (k < 48)  v = mean[(64+b)*16 + (k-32)];
            else              v = expf(0.5f * mean[(64+b)*16 + (k-48)]);
            feat[k] = v;
        }
        __syncthreads();
        for (int j = t; j < 288; j += 256) {
            float a = lin_b[j];
            const float* wr = lin_w + j*64;
            #pragma unroll
            for (int k = 0; k < 64; ++k) a += feat[k]*wr[k];
            probb[j] = a;
        }
        __syncthreads();
        if (t < 16) {
            int s = t;
            float l0 = probb[2*s], l1 = probb[2*s+1];
            float M = fmaxf(l0,l1);
            float e0 = expf(l0-M), e1 = expf(l1-M);
            float Z = e0+e1;
            float p0 = e0/Z, p1 = e1/Z;
            float M2 = fmaxf(p0,p1);
            float lse = M2 + logf(expf(p0-M2)+expf(p1-M2));
            float ls0 = p0 - lse, ls1 = p1 - lse;
            float z1v = latent[b*16+s], z2v = latent[(64+b)*16+s];
            int tt = (fabsf(z1v - z2v) > 0.2f) ? 1 : 0;
            red16[s] = -(tt ? ls1 : ls0);
            int r = b*16 + s;
            float x0 = (l0 + gumbel[2*r])   * 10000.0f;
            float x1 = (l1 + gumbel[2*r+1]) * 10000.0f;
            float Ma = fmaxf(x0,x1);
            float a0 = expf(x0-Ma), a1 = expf(x1-Ma);
            float Za = a0+a1;
            a0 /= Za; a1 /= Za;
            float sw = ((a0 >= 0.5f) || (a1 > 0.5f)) ? a1 : 0.0f;
            out[O_ATTN + b*272 + s] = sw;
            const float* fl = &probb[32 + s*16];
            float mf = fl[0];
            #pragma unroll
            for (int u = 1; u < 16; ++u) mf = fmaxf(mf, fl[u]);
            float ex[16]; float Zf = 0.f;
            #pragma unroll
            for (int u = 0; u < 16; ++u) { ex[u] = expf(fl[u]-mf); Zf += ex[u]; }
            float rZ = 1.0f/Zf;
            #pragma unroll
            for (int u = 0; u < 16; ++u) {
                float fp = ex[u]*rZ;
                out[O_ATTN + b*272 + 16 + s*16 + u] = fp;
                wrow[s*16 + u] = sw*fp;
            }
        }
        __syncthreads();
        if (t == 0) {
            float s = 0.f;
            for (int i = 0; i < 16; ++i) s += red16[i];
            atomicAdd(&acc[0], (double)s);
        }
        // ssyms: per-thread element t of each 16x16 matrix
        float Stot = 0.f;
        for (int s = 0; s < 16; ++s) {
            float a = 0.f;
            #pragma unroll
            for (int u = 0; u < 16; ++u)
                a += wrow[s*16+u] * ge[(s*16+u)*256 + t];
            out[O_SUB + b*4096 + s*256 + t] = a;
            Stot += a;
        }
        S_ws[b*256 + t] = Stot;
    } else if (bid < 320) {
        int e = bid - 64;
        expm_block(ge + e*256, 1.0f, syms + e*256, nullptr, smem, &shi, t);
    } else {
        // ---- commut pair ----
        int idx = bid - 320;
        float* G = smem;             // 4096
        float* gA = smem + 4096;     // 256
        float* gB = smem + 4352;     // 256
        float* red = smem + 4608;    // 256
        int a2 = 0, cnt = 15, rem = idx;
        while (rem >= cnt) { rem -= cnt; a2++; cnt--; }
        int b2 = a2 + 1 + rem;
        #pragma unroll
        for (int q = 0; q < 16; ++q) {
            int ii = t + 256*q;
            int k = ii >> 8, x = ii & 255;
            G[ii] = ge[k*16*256 + x];
        }
        gA[t] = ge[a2*256+t];
        gB[t] = ge[b2*256+t];
        __syncthreads();
        int i = t >> 4, j = t & 15;
        float v1 = 0.f, v2 = 0.f;
        #pragma unroll
        for (int k = 0; k < 16; ++k) {
            v1 += gA[i*16+k]*G[k*256 + b2*16 + j];
            v2 += gB[i*16+k]*G[k*256 + a2*16 + j];
        }
        float d = v1 - v2;
        red[t] = d*d;
        __syncthreads();
        for (int off = 128; off > 0; off >>= 1) { if (t < off) red[t] += red[t+off]; __syncthreads(); }
        if (t == 0) c_pairs[idx] = 2.0f*red[0];
    }
}

// ---------------- K2: [0,128) expm(+-S) | [128,384) diff+rinv+sparse ----------------
__global__ void k_stage2(const float* __restrict__ latent, const float* __restrict__ S_ws,
                         const float* __restrict__ syms,
                         float* __restrict__ fwdS, float* __restrict__ invS,
                         float* __restrict__ diff, float* __restrict__ rinv,
                         float* __restrict__ out, double* __restrict__ acc)
{
    __shared__ float smem[4608];
    __shared__ int shi;
    int bid = blockIdx.x;
    int t = threadIdx.x;
    if (bid < 64) {
        int b = bid;
        expm_block(S_ws + b*256, 1.0f, fwdS + b*256, out + O_FWD + b*256, smem, &shi, t);
    } else if (bid < 128) {
        int b = bid - 64;
        expm_block(S_ws + b*256, -1.0f, invS + b*256, nullptr, smem, &shi, t);
    } else {
        int e = bid - 128;
        float* zsh = smem;          // 2048
        float* ssh = smem + 2048;   // 256
        float* dsh = smem + 2304;   // 2048
        float* red = smem + 4352;   // 256
        ssh[t] = syms[e*256+t];
        #pragma unroll
        for (int q = 0; q < 8; ++q) zsh[t+256*q] = latent[t+256*q];
        __syncthreads();
        #pragma unroll
        for (int q = 0; q < 8; ++q) {
            int idx = t + 256*q;
            int b = idx >> 4, d = idx & 15;
            float a = 0.f;
            #pragma unroll
            for (int k = 0; k < 16; ++k) a += zsh[b*16+k]*ssh[k*16+d];
            float v = zsh[idx] - a;
            dsh[idx] = v;
            diff[(size_t)e*2048 + idx] = v;
        }
        __syncthreads();
        float part = 0.f;
        if (t < 128) {
            float sum = 0.f, mx = 0.f;
            #pragma unroll
            for (int d = 0; d < 16; ++d) {
                float v = dsh[t*16+d];
                float v2 = v*v;
                sum += v2; mx = fmaxf(mx, v2);
            }
            float sm2 = sum - mx;
            part = sm2*sm2;
            rinv[e*128+t] = 1.0f/sqrtf(sum);
        }
        block_reduce_to(part, red, t, &acc[1], 1.0f);
    }
}

// ---------------- K3: [0,2176) parallel (tm<=tn) | [2176,2296) orth (sm<sn) | [2296,2300) tz ----------------
__global__ void __launch_bounds__(256) k_stage3(const float* __restrict__ diff,
                                                const float* __restrict__ rinv,
                                                const float* __restrict__ latent,
                                                const float* __restrict__ fwdS,
                                                const float* __restrict__ invS,
                                                const int* __restrict__ sec_idx,
                                                float* __restrict__ out, double* __restrict__ acc)
{
    __shared__ float red[256];
    int bid = blockIdx.x;
    int t = threadIdx.x;
    if (bid < 2176) {
        int s = bid / 136;
        int r = bid % 136;
        int tm = 0;
        while (r >= 16 - tm) { r -= 16 - tm; tm++; }
        int tn = tm + r;
        int baseM = s*2048 + tm*128;
        int baseN = s*2048 + tn*128;
        float accf = tile_core<true>(diff, rinv, baseM, baseN, t);
        float wt = (tm == tn) ? 1.0f : 2.0f;
        block_reduce_to(accf, red, t, &acc[2], wt);
    } else if (bid < 2296) {
        int idx = bid - 2176;
        int sm = 0, cnt = 15, rem = idx;
        while (rem >= cnt) { rem -= cnt; sm++; cnt--; }
        int sn = sm + 1 + rem;
        int em = sm*16 + sec_idx[sm];
        int en = sn*16 + sec_idx[sn];
        float accf = tile_core<false>(diff, rinv, em*128, en*128, t);
        block_reduce_to(accf, red, t, &acc[3], 2.0f);
    } else {
        int g = (bid - 2296)*256 + t;   // 0..1023
        int b = g >> 4, d = g & 15;     // b < 64
        float t1 = 0.f, t2 = 0.f;
        #pragma unroll
        for (int k = 0; k < 16; ++k) {
            t1 += latent[b*16+k]      * fwdS[b*256 + k*16 + d];
            t2 += latent[(64+b)*16+k] * invS[b*256 + k*16 + d];
        }
        out[O_TZ1 + g] = t1;
        out[O_TZ2 + g] = t2;
        float z1v = latent[b*16+d], z2v = latent[(64+b)*16+d];
        float ep = (t2 - z1v)*(t2 - z1v) + (t1 - z2v)*(t1 - z2v);
        block_reduce_to(ep, red, t, &acc[4], 1.0f);
    }
}

// ---------------- K4: final scalar assembly ----------------
__global__ void k_final(const float* __restrict__ c_pairs, const double* __restrict__ acc,
                        float* __restrict__ out)
{
    int t = threadIdx.x;
    __shared__ float red[128];
    float v = 0.f;
    if (t < 120) v = (float)(120 - t) * c_pairs[t];
    red[t] = v;
    __syncthreads();
    for (int off = 64; off > 0; off >>= 1) { if (t < off) red[t] += red[t+off]; __syncthreads(); }
    if (t == 0) {
        out[O_COMM]    = red[0] / 16777216.0f;                       // /(DIM*E)^2
        out[O_EQUI]    = (float)(acc[4] / 1024.0);
        out[O_ORTH]    = (float)(acc[3] / (2048.0*2048.0));
        out[O_PAR]     = (float)(-(acc[2]) * 0.6931471805599453 / 67108864.0);  // log2->ln, mean, negate
        out[O_SPARSE]  = (float)(acc[1] / 32768.0);
        out[O_SECLOSS] = (float)(acc[0] / 64.0);
    }
}

extern "C" void kernel_launch(void* const* d_in, const int* in_sizes, int n_in,
                              void* d_out, int out_size, void* d_ws, size_t ws_size,
                              hipStream_t stream)
{
    const float* mean    = (const float*)d_in[0];
    const float* logvar  = (const float*)d_in[1];
    const float* latent  = (const float*)d_in[2];
    const float* ge      = (const float*)d_in[3];
    const float* lin_w   = (const float*)d_in[4];
    const float* lin_b   = (const float*)d_in[5];
    const float* gumbel  = (const float*)d_in[6];
    const int*   sec_idx = (const int*)d_in[7];
    float* out = (float*)d_out;

    char* ws = (char*)d_ws;
    double* acc     = (double*)ws;          // 5 doubles
    float* c_pairs  = (float*)(ws + 64);    // 120 floats
    float* fbase    = (float*)(ws + 1024);
    float* S_ws = fbase;                    // 16384
    float* syms = fbase + 16384;            // 65536
    float* fwdS = fbase + 81920;            // 16384
    float* invS = fbase + 98304;            // 16384
    float* diff = fbase + 114688;           // 524288
    float* rinv = fbase + 638976;           // 32768

    hipMemsetAsync(ws, 0, 1024, stream);
    k_stage1<<<440,  256, 0, stream>>>(mean, logvar, latent, ge, lin_w, lin_b, gumbel,
                                       out, S_ws, syms, c_pairs, acc);
    k_stage2<<<384,  256, 0, stream>>>(latent, S_ws, syms, fwdS, invS, diff, rinv, out, acc);
    k_stage3<<<2300, 256, 0, stream>>>(diff, rinv, latent, fwdS, invS, sec_idx, out, acc);
    k_final <<<1,    128, 0, stream>>>(c_pairs, acc, out);
}

// Round 4
// 125.617 us; speedup vs baseline: 1.4603x; 1.1390x over previous
//
#include <hip/hip_runtime.h>
#include <math.h>

// output offsets (floats)
#define O_TZ1      0
#define O_TZ2      1024
#define O_FWD      2048
#define O_EQUI     18432
#define O_ATTN     18433
#define O_ORTH     35841
#define O_PAR      35842
#define O_COMM     35843
#define O_SPARSE   35844
#define O_SECLOSS  35845
#define O_SUB      35846

// ---------------- shared device helpers ----------------

__device__ __forceinline__ void block_reduce_to(float v, float* red, int t, double* dst, float scale)
{
    red[t] = v;
    __syncthreads();
    for (int off = 128; off > 0; off >>= 1) { if (t < off) red[t] += red[t+off]; __syncthreads(); }
    if (t == 0) atomicAdd(dst, (double)(red[0] * scale));
}

// expm via scaling-squaring + Taylor-8 (scaled norm <= 0.66; trunc err ~7e-8 rel)
__device__ __forceinline__ void expm_block(const float* __restrict__ src, float sign,
                                           float* __restrict__ dst, float* __restrict__ dst2,
                                           float* sm, int* shi, int t)
{
    float* As = sm; float* T = sm + 256; float* P = sm + 512; float* rowsum = sm + 768;
    float a = src[t];
    As[t] = a;
    __syncthreads();
    if (t < 16) {
        float rs = 0.f;
        #pragma unroll
        for (int k = 0; k < 16; ++k) rs += fabsf(As[t*16+k]);
        rowsum[t] = rs;
    }
    __syncthreads();
    if (t == 0) {
        float nrm = 0.f;
        for (int i = 0; i < 16; ++i) nrm = fmaxf(nrm, rowsum[i]);
        int s = 0;
        if (nrm > 0.66f) { s = (int)ceilf(log2f(nrm * 1.51515f)); if (s < 0) s = 0; }
        *shi = s;
    }
    __syncthreads();
    int sq = *shi;
    float scale = sign * exp2f((float)(-sq));
    int i = t >> 4, j = t & 15;
    float as = a * scale;
    As[t] = as;
    T[t]  = ((i==j) ? 1.0f : 0.0f) + as;
    P[t]  = as;
    __syncthreads();
    for (int k = 2; k <= 8; ++k) {
        float accv = 0.f;
        #pragma unroll
        for (int m = 0; m < 16; ++m) accv += P[i*16+m]*As[m*16+j];
        float rk = 1.0f/(float)k;
        __syncthreads();
        float term = accv * rk;
        P[t] = term;
        T[t] += term;
        __syncthreads();
    }
    for (int q = 0; q < sq; ++q) {
        float accv = 0.f;
        #pragma unroll
        for (int m = 0; m < 16; ++m) accv += T[i*16+m]*T[m*16+j];
        __syncthreads();
        T[t] = accv;
        __syncthreads();
    }
    dst[t] = T[t];
    if (dst2) dst2[t] = T[t];
}

// gram-tile core v2: M-fragment in explicit float4 registers (2 rows/thread),
// N-tile staged in LDS, read as b128 broadcast (16 lanes/address -> conflict-free).
template <bool DO_LOG>
__device__ __forceinline__ float tile_core2(const float* __restrict__ diff,
                                            const float* __restrict__ rinv,
                                            float4* tN4, float* rNs,
                                            int baseM, int baseN, int t)
{
    const float4* gd4 = (const float4*)diff;
    tN4[t]       = gd4[baseN*4 + t];
    tN4[t + 256] = gd4[baseN*4 + 256 + t];
    if (t < 128) rNs[t] = rinv[baseN + t];
    int rp = t >> 2, cg = t & 3;
    int m0 = baseM + rp*2;
    const float4* mp = gd4 + (size_t)m0*4;
    float4 a0 = mp[0], a1 = mp[1], a2 = mp[2], a3 = mp[3];
    float4 b0 = mp[4], b1 = mp[5], b2 = mp[6], b3 = mp[7];
    float ri0 = rinv[m0], ri1 = rinv[m0+1];
    __syncthreads();
    float acc0 = 0.f, acc1 = 0.f;
    #pragma unroll 4
    for (int jj = 0; jj < 32; ++jj) {
        int nj = cg + 4*jj;
        float4 n0 = tN4[nj*4+0], n1 = tN4[nj*4+1], n2 = tN4[nj*4+2], n3 = tN4[nj*4+3];
        float rn = rNs[nj];
        float d0 = a0.x*n0.x + a0.y*n0.y + a0.z*n0.z + a0.w*n0.w
                 + a1.x*n1.x + a1.y*n1.y + a1.z*n1.z + a1.w*n1.w
                 + a2.x*n2.x + a2.y*n2.y + a2.z*n2.z + a2.w*n2.w
                 + a3.x*n3.x + a3.y*n3.y + a3.z*n3.z + a3.w*n3.w;
        float d1 = b0.x*n0.x + b0.y*n0.y + b0.z*n0.z + b0.w*n0.w
                 + b1.x*n1.x + b1.y*n1.y + b1.z*n1.z + b1.w*n1.w
                 + b2.x*n2.x + b2.y*n2.y + b2.z*n2.z + b2.w*n2.w
                 + b3.x*n3.x + b3.y*n3.y + b3.z*n3.z + b3.w*n3.w;
        float s0 = d0 * ri0 * rn;
        float s1 = d1 * ri1 * rn;
        if (DO_LOG) {
            acc0 += __log2f(s0*s0 + 1e-9f);
            acc1 += __log2f(s1*s1 + 1e-9f);
        } else {
            acc0 += s0*s0;
            acc1 += s1*s1;
        }
    }
    return acc0 + acc1;
}

// ---------------- K1: [0,64) prob+ssyms | [64,320) expm(ge) | [320,440) commut ----------------
__global__ void k_stage1(const float* __restrict__ mean, const float* __restrict__ logvar,
                         const float* __restrict__ latent, const float* __restrict__ ge,
                         const float* __restrict__ lin_w, const float* __restrict__ lin_b,
                         const float* __restrict__ gumbel,
                         float* __restrict__ out, float* __restrict__ S_ws,
                         float* __restrict__ syms, float* __restrict__ c_pairs,
                         double* __restrict__ acc)
{
    __shared__ float smem[4864];
    __shared__ int shi;
    int bid = blockIdx.x;
    int t = threadIdx.x;

    if (bid < 64) {
        // ---- prob + ssyms for b = bid ----
        int b = bid;
        float* feat = smem;            // 64
        float* probb = smem + 64;      // 288
        float* red16 = smem + 352;     // 16
        float* wrow = smem + 368;      // 256
        if (t < 64) {
            int k = t; float v;
            if (k < 16)       v = mean[b*16 + k];
            else if (k < 32)  v = expf(0.5f * logvar[b*16 + (k-16)]);
            else if (k < 48)  v = mean[(64+b)*16 + (k-32)];
            else              v = expf(0.5f * mean[(64+b)*16 + (k-48)]);
            feat[k] = v;
        }
        __syncthreads();
        for (int j = t; j < 288; j += 256) {
            float a = lin_b[j];
            const float* wr = lin_w + j*64;
            #pragma unroll
            for (int k = 0; k < 64; ++k) a += feat[k]*wr[k];
            probb[j] = a;
        }
        __syncthreads();
        if (t < 16) {
            int s = t;
            float l0 = probb[2*s], l1 = probb[2*s+1];
            float M = fmaxf(l0,l1);
            float e0 = expf(l0-M), e1 = expf(l1-M);
            float Z = e0+e1;
            float p0 = e0/Z, p1 = e1/Z;
            float M2 = fmaxf(p0,p1);
            float lse = M2 + logf(expf(p0-M2)+expf(p1-M2));
            float ls0 = p0 - lse, ls1 = p1 - lse;
            float z1v = latent[b*16+s], z2v = latent[(64+b)*16+s];
            int tt = (fabsf(z1v - z2v) > 0.2f) ? 1 : 0;
            red16[s] = -(tt ? ls1 : ls0);
            int r = b*16 + s;
            float x0 = (l0 + gumbel[2*r])   * 10000.0f;
            float x1 = (l1 + gumbel[2*r+1]) * 10000.0f;
            float Ma = fmaxf(x0,x1);
            float a0 = expf(x0-Ma), a1 = expf(x1-Ma);
            float Za = a0+a1;
            a0 /= Za; a1 /= Za;
            float sw = ((a0 >= 0.5f) || (a1 > 0.5f)) ? a1 : 0.0f;
            out[O_ATTN + b*272 + s] = sw;
            const float* fl = &probb[32 + s*16];
            float mf = fl[0];
            #pragma unroll
            for (int u = 1; u < 16; ++u) mf = fmaxf(mf, fl[u]);
            float ex[16]; float Zf = 0.f;
            #pragma unroll
            for (int u = 0; u < 16; ++u) { ex[u] = expf(fl[u]-mf); Zf += ex[u]; }
            float rZ = 1.0f/Zf;
            #pragma unroll
            for (int u = 0; u < 16; ++u) {
                float fp = ex[u]*rZ;
                out[O_ATTN + b*272 + 16 + s*16 + u] = fp;
                wrow[s*16 + u] = sw*fp;
            }
        }
        __syncthreads();
        if (t == 0) {
            float s = 0.f;
            for (int i = 0; i < 16; ++i) s += red16[i];
            atomicAdd(&acc[0], (double)s);
        }
        // ssyms: per-thread element t of each 16x16 matrix
        float Stot = 0.f;
        for (int s = 0; s < 16; ++s) {
            float a = 0.f;
            #pragma unroll
            for (int u = 0; u < 16; ++u)
                a += wrow[s*16+u] * ge[(s*16+u)*256 + t];
            out[O_SUB + b*4096 + s*256 + t] = a;
            Stot += a;
        }
        S_ws[b*256 + t] = Stot;
    } else if (bid < 320) {
        int e = bid - 64;
        expm_block(ge + e*256, 1.0f, syms + e*256, nullptr, smem, &shi, t);
    } else {
        // ---- commut pair ----
        int idx = bid - 320;
        float* G = smem;             // 4096
        float* gA = smem + 4096;     // 256
        float* gB = smem + 4352;     // 256
        float* red = smem + 4608;    // 256
        int a2 = 0, cnt = 15, rem = idx;
        while (rem >= cnt) { rem -= cnt; a2++; cnt--; }
        int b2 = a2 + 1 + rem;
        #pragma unroll
        for (int q = 0; q < 16; ++q) {
            int ii = t + 256*q;
            int k = ii >> 8, x = ii & 255;
            G[ii] = ge[k*16*256 + x];
        }
        gA[t] = ge[a2*256+t];
        gB[t] = ge[b2*256+t];
        __syncthreads();
        int i = t >> 4, j = t & 15;
        float v1 = 0.f, v2 = 0.f;
        #pragma unroll
        for (int k = 0; k < 16; ++k) {
            v1 += gA[i*16+k]*G[k*256 + b2*16 + j];
            v2 += gB[i*16+k]*G[k*256 + a2*16 + j];
        }
        float d = v1 - v2;
        red[t] = d*d;
        __syncthreads();
        for (int off = 128; off > 0; off >>= 1) { if (t < off) red[t] += red[t+off]; __syncthreads(); }
        if (t == 0) c_pairs[idx] = 2.0f*red[0];
    }
}

// ---------------- K2: [0,128) expm(+-S) | [128,384) diff+rinv+sparse ----------------
__global__ void k_stage2(const float* __restrict__ latent, const float* __restrict__ S_ws,
                         const float* __restrict__ syms,
                         float* __restrict__ fwdS, float* __restrict__ invS,
                         float* __restrict__ diff, float* __restrict__ rinv,
                         float* __restrict__ out, double* __restrict__ acc)
{
    __shared__ float smem[4608];
    __shared__ int shi;
    int bid = blockIdx.x;
    int t = threadIdx.x;
    if (bid < 64) {
        int b = bid;
        expm_block(S_ws + b*256, 1.0f, fwdS + b*256, out + O_FWD + b*256, smem, &shi, t);
    } else if (bid < 128) {
        int b = bid - 64;
        expm_block(S_ws + b*256, -1.0f, invS + b*256, nullptr, smem, &shi, t);
    } else {
        int e = bid - 128;
        float* zsh = smem;          // 2048
        float* ssh = smem + 2048;   // 256
        float* dsh = smem + 2304;   // 2048
        float* red = smem + 4352;   // 256
        ssh[t] = syms[e*256+t];
        #pragma unroll
        for (int q = 0; q < 8; ++q) zsh[t+256*q] = latent[t+256*q];
        __syncthreads();
        #pragma unroll
        for (int q = 0; q < 8; ++q) {
            int idx = t + 256*q;
            int b = idx >> 4, d = idx & 15;
            float a = 0.f;
            #pragma unroll
            for (int k = 0; k < 16; ++k) a += zsh[b*16+k]*ssh[k*16+d];
            float v = zsh[idx] - a;
            dsh[idx] = v;
            diff[(size_t)e*2048 + idx] = v;
        }
        __syncthreads();
        float part = 0.f;
        if (t < 128) {
            float sum = 0.f, mx = 0.f;
            #pragma unroll
            for (int d = 0; d < 16; ++d) {
                float v = dsh[t*16+d];
                float v2 = v*v;
                sum += v2; mx = fmaxf(mx, v2);
            }
            float sm2 = sum - mx;
            part = sm2*sm2;
            rinv[e*128+t] = 1.0f/sqrtf(sum);
        }
        block_reduce_to(part, red, t, &acc[1], 1.0f);
    }
}

// ---------------- K3: [0,2176) parallel (tm<=tn) | [2176,2296) orth (sm<sn) | [2296,2300) tz ----------------
__global__ void __launch_bounds__(256) k_stage3(const float* __restrict__ diff,
                                                const float* __restrict__ rinv,
                                                const float* __restrict__ latent,
                                                const float* __restrict__ fwdS,
                                                const float* __restrict__ invS,
                                                const int* __restrict__ sec_idx,
                                                float* __restrict__ out, double* __restrict__ acc)
{
    __shared__ __attribute__((aligned(16))) float4 tN4[512];
    __shared__ float rNs[128];
    __shared__ float red[256];
    int bid = blockIdx.x;
    int t = threadIdx.x;
    if (bid < 2176) {
        int s = bid / 136;
        int r = bid % 136;
        int tm = 0;
        while (r >= 16 - tm) { r -= 16 - tm; tm++; }
        int tn = tm + r;
        int baseM = s*2048 + tm*128;
        int baseN = s*2048 + tn*128;
        float accf = tile_core2<true>(diff, rinv, tN4, rNs, baseM, baseN, t);
        float wt = (tm == tn) ? 1.0f : 2.0f;
        block_reduce_to(accf, red, t, &acc[2], wt);
    } else if (bid < 2296) {
        int idx = bid - 2176;
        int sm = 0, cnt = 15, rem = idx;
        while (rem >= cnt) { rem -= cnt; sm++; cnt--; }
        int sn = sm + 1 + rem;
        int em = sm*16 + sec_idx[sm];
        int en = sn*16 + sec_idx[sn];
        float accf = tile_core2<false>(diff, rinv, tN4, rNs, em*128, en*128, t);
        block_reduce_to(accf, red, t, &acc[3], 2.0f);
    } else {
        int g = (bid - 2296)*256 + t;   // 0..1023
        int b = g >> 4, d = g & 15;     // b < 64
        float t1 = 0.f, t2 = 0.f;
        #pragma unroll
        for (int k = 0; k < 16; ++k) {
            t1 += latent[b*16+k]      * fwdS[b*256 + k*16 + d];
            t2 += latent[(64+b)*16+k] * invS[b*256 + k*16 + d];
        }
        out[O_TZ1 + g] = t1;
        out[O_TZ2 + g] = t2;
        float z1v = latent[b*16+d], z2v = latent[(64+b)*16+d];
        float ep = (t2 - z1v)*(t2 - z1v) + (t1 - z2v)*(t1 - z2v);
        block_reduce_to(ep, red, t, &acc[4], 1.0f);
    }
}

// ---------------- K4: final scalar assembly ----------------
__global__ void k_final(const float* __restrict__ c_pairs, const double* __restrict__ acc,
                        float* __restrict__ out)
{
    int t = threadIdx.x;
    __shared__ float red[128];
    float v = 0.f;
    if (t < 120) v = (float)(120 - t) * c_pairs[t];
    red[t] = v;
    __syncthreads();
    for (int off = 64; off > 0; off >>= 1) { if (t < off) red[t] += red[t+off]; __syncthreads(); }
    if (t == 0) {
        out[O_COMM]    = red[0] / 16777216.0f;                       // /(DIM*E)^2
        out[O_EQUI]    = (float)(acc[4] / 1024.0);
        out[O_ORTH]    = (float)(acc[3] / (2048.0*2048.0));
        out[O_PAR]     = (float)(-(acc[2]) * 0.6931471805599453 / 67108864.0);  // log2->ln, mean, negate
        out[O_SPARSE]  = (float)(acc[1] / 32768.0);
        out[O_SECLOSS] = (float)(acc[0] / 64.0);
    }
}

extern "C" void kernel_launch(void* const* d_in, const int* in_sizes, int n_in,
                              void* d_out, int out_size, void* d_ws, size_t ws_size,
                              hipStream_t stream)
{
    const float* mean    = (const float*)d_in[0];
    const float* logvar  = (const float*)d_in[1];
    const float* latent  = (const float*)d_in[2];
    const float* ge      = (const float*)d_in[3];
    const float* lin_w   = (const float*)d_in[4];
    const float* lin_b   = (const float*)d_in[5];
    const float* gumbel  = (const float*)d_in[6];
    const int*   sec_idx = (const int*)d_in[7];
    float* out = (float*)d_out;

    char* ws = (char*)d_ws;
    double* acc     = (double*)ws;          // 5 doubles
    float* c_pairs  = (float*)(ws + 64);    // 120 floats
    float* fbase    = (float*)(ws + 1024);
    float* S_ws = fbase;                    // 16384
    float* syms = fbase + 16384;            // 65536
    float* fwdS = fbase + 81920;            // 16384
    float* invS = fbase + 98304;            // 16384
    float* diff = fbase + 114688;           // 524288
    float* rinv = fbase + 638976;           // 32768

    hipMemsetAsync(ws, 0, 1024, stream);
    k_stage1<<<440,  256, 0, stream>>>(mean, logvar, latent, ge, lin_w, lin_b, gumbel,
                                       out, S_ws, syms, c_pairs, acc);
    k_stage2<<<384,  256, 0, stream>>>(latent, S_ws, syms, fwdS, invS, diff, rinv, out, acc);
    k_stage3<<<2300, 256, 0, stream>>>(diff, rinv, latent, fwdS, invS, sec_idx, out, acc);
    k_final <<<1,    128, 0, stream>>>(c_pairs, acc, out);
}